// Round 1
// baseline (249.510 us; speedup 1.0000x reference)
//
#include <hip/hip_runtime.h>
#include <math.h>

// Problem constants (B=1)
#define TT   512
#define CEMB 768
#define NH   12
#define NKV  6
#define HD   64
#define KVC  (NKV*HD)   // 384

__device__ __forceinline__ float wave_max(float v){
  #pragma unroll
  for(int o=32;o>0;o>>=1) v = fmaxf(v, __shfl_xor(v, o));
  return v;
}
__device__ __forceinline__ float wave_sum(float v){
  #pragma unroll
  for(int o=32;o>0;o>>=1) v += __shfl_xor(v, o);
  return v;
}

// ---- fp32 GEMM core: 64x64 tile, BK=16, 256 threads, 4x4 microtile ----
__device__ __forceinline__ void gemm_core(const float* __restrict__ A,
                                          const float* __restrict__ B,
                                          float* __restrict__ C,
                                          int K, int lda, int ldb, int ldc,
                                          int m0, int n0){
  __shared__ float As[16][64];
  __shared__ float Bs[16][64];
  int tid  = threadIdx.x;
  int arow = tid >> 2, akv = (tid & 3) * 4;     // A: 64 rows x 16 k, one float4/thread
  int brow = tid >> 4, bcol = (tid & 15) * 4;   // B: 16 rows x 64 n, one float4/thread
  int ty   = tid >> 4, tx = tid & 15;
  float acc[4][4];
  #pragma unroll
  for(int i=0;i<4;i++)
    #pragma unroll
    for(int j=0;j<4;j++) acc[i][j] = 0.f;

  for(int k0=0;k0<K;k0+=16){
    float4 a = *(const float4*)(A + (size_t)(m0+arow)*lda + k0 + akv);
    float4 b = *(const float4*)(B + (size_t)(k0+brow)*ldb + n0 + bcol);
    As[akv+0][arow]=a.x; As[akv+1][arow]=a.y; As[akv+2][arow]=a.z; As[akv+3][arow]=a.w;
    *(float4*)(&Bs[brow][bcol]) = b;
    __syncthreads();
    #pragma unroll
    for(int kk=0;kk<16;kk++){
      float4 av = *(float4*)(&As[kk][ty*4]);
      float4 bv = *(float4*)(&Bs[kk][tx*4]);
      float av_[4] = {av.x, av.y, av.z, av.w};
      float bv_[4] = {bv.x, bv.y, bv.z, bv.w};
      #pragma unroll
      for(int ii=0; ii<4; ii++)
        #pragma unroll
        for(int jj=0; jj<4; jj++)
          acc[ii][jj] = fmaf(av_[ii], bv_[jj], acc[ii][jj]);
    }
    __syncthreads();
  }
  #pragma unroll
  for(int i=0;i<4;i++){
    float4 o = make_float4(acc[i][0],acc[i][1],acc[i][2],acc[i][3]);
    *(float4*)(C + (size_t)(m0+ty*4+i)*ldc + n0 + tx*4) = o;
  }
}

// QKV projection: X(512x768) @ [Wq(768x768) | Wk(768x384) | Wv(768x384)]
__global__ void __launch_bounds__(256) gemm_qkv(const float* __restrict__ X,
    const float* __restrict__ Wq, const float* __restrict__ Wk, const float* __restrict__ Wv,
    float* __restrict__ q, float* __restrict__ k, float* __restrict__ v){
  int mt = blockIdx.x;       // 0..7
  int nt = blockIdx.y;       // 0..23
  const float* B; float* C; int ldb, ldc, n0;
  if (nt < 12)      { B = Wq; C = q; ldb = CEMB; ldc = CEMB; n0 = nt*64; }
  else if (nt < 18) { B = Wk; C = k; ldb = KVC;  ldc = KVC;  n0 = (nt-12)*64; }
  else              { B = Wv; C = v; ldb = KVC;  ldc = KVC;  n0 = (nt-18)*64; }
  gemm_core(X, B, C, CEMB, CEMB, ldb, ldc, mt*64, n0);
}

// Output projection: Y(512x768) @ Wproj(768x768)
__global__ void __launch_bounds__(256) gemm_proj(const float* __restrict__ Y,
    const float* __restrict__ Wp, float* __restrict__ C){
  gemm_core(Y, Wp, C, CEMB, CEMB, CEMB, CEMB, blockIdx.x*64, blockIdx.y*64);
}

// RoPE + RMSNorm, in-place on q (512x768) and k (512x384). One wave = one (t, head).
__global__ void __launch_bounds__(256) rope_rms(float* __restrict__ q, float* __restrict__ k,
    const float* __restrict__ cosb, const float* __restrict__ sinb){
  int wid  = (blockIdx.x * blockDim.x + threadIdx.x) >> 6;
  int lane = threadIdx.x & 63;
  float* base; int t;
  if (wid < TT*NH){
    t = wid / NH; int h = wid % NH;
    base = q + (size_t)t*CEMB + h*HD;
  } else {
    int w2 = wid - TT*NH;
    t = w2 / NKV; int h = w2 % NKV;
    base = k + (size_t)t*KVC + h*HD;
  }
  float v = base[lane];
  int dh = lane & 31;
  float c = cosb[t*32 + dh];
  float s = sinb[t*32 + dh];
  float partner = __shfl_xor(v, 32);
  float rot = (lane < 32) ? (v*c - partner*s) : (v*c + partner*s);
  float ss = wave_sum(rot*rot);
  float scale = rsqrtf(ss * (1.0f/64.0f) + 1e-6f);
  base[lane] = rot * scale;
}

// Tropical causal attention, flash-style online softmax.
// One wave per query row; block = 4 consecutive rows of one head.
__global__ void __launch_bounds__(256) attn_kernel(const float* __restrict__ qn,
    const float* __restrict__ kn, const float* __restrict__ vr, float* __restrict__ y){
  __shared__ float Ksh[64*65];
  __shared__ float Vsh[64*65];
  __shared__ float Qsh[4*64];
  __shared__ float Psh[4*64];
  int h    = blockIdx.x >> 7;       // /128
  int qblk = blockIdx.x & 127;
  int w    = threadIdx.x >> 6;
  int lane = threadIdx.x & 63;
  int i    = qblk*4 + w;
  int kvh  = h >> 1;                // n_rep = 2

  Qsh[w*64 + lane] = qn[(size_t)i*CEMB + h*HD + lane];

  float m = -INFINITY, l = 0.f, yacc = 0.f;
  int ntiles = ((qblk*4 + 3) >> 6) + 1;   // block-uniform

  for(int tt=0; tt<ntiles; ++tt){
    int t0 = tt*64;
    __syncthreads();   // protect Ksh/Vsh reuse; also orders Qsh writes on first iter
    for(int r=w; r<64; r+=4){
      Ksh[r*65 + lane] = kn[(size_t)(t0+r)*KVC + kvh*HD + lane];
      Vsh[r*65 + lane] = vr[(size_t)(t0+r)*KVC + kvh*HD + lane];
    }
    __syncthreads();
    if (t0 <= i){
      // scores: lane = j within tile
      float s = -INFINITY;
      const float* qrow = &Qsh[w*64];
      #pragma unroll 8
      for(int d=0; d<64; ++d)
        s = fmaxf(s, qrow[d] + Ksh[lane*65 + d]);
      if (t0 + lane > i) s = -INFINITY;     // causal mask

      float mt    = wave_max(s);
      float m_new = fmaxf(m, mt);
      float corr  = __expf(m - m_new);      // 0 on first tile (m = -inf)
      float p     = __expf(s - m_new);      // 0 for masked lanes
      l    = l*corr + wave_sum(p);
      yacc = yacc*corr;

      Psh[w*64 + lane] = p;
      __builtin_amdgcn_wave_barrier();      // DS in-order per wave; block compiler reordering
      #pragma unroll 8
      for(int j=0;j<64;++j)
        yacc = fmaf(Psh[w*64 + j], Vsh[j*65 + lane], yacc);
      __builtin_amdgcn_wave_barrier();
      m = m_new;
    }
  }
  y[(size_t)i*CEMB + h*HD + lane] = yacc / l;
}

extern "C" void kernel_launch(void* const* d_in, const int* in_sizes, int n_in,
                              void* d_out, int out_size, void* d_ws, size_t ws_size,
                              hipStream_t stream){
  const float* x    = (const float*)d_in[0];
  const float* cosb = (const float*)d_in[1];
  const float* sinb = (const float*)d_in[2];
  const float* Wq   = (const float*)d_in[3];
  const float* Wk   = (const float*)d_in[4];
  const float* Wv   = (const float*)d_in[5];
  const float* Wp   = (const float*)d_in[6];
  float* out = (float*)d_out;

  float* ws    = (float*)d_ws;
  float* q_raw = ws;                          // 512*768
  float* k_raw = q_raw + TT*CEMB;             // 512*384
  float* v_raw = k_raw + TT*KVC;              // 512*384
  float* ybuf  = v_raw + TT*KVC;              // 512*768

  gemm_qkv  <<<dim3(8,24), 256, 0, stream>>>(x, Wq, Wk, Wv, q_raw, k_raw, v_raw);
  rope_rms  <<<dim3((TT*NH + TT*NKV)/4), 256, 0, stream>>>(q_raw, k_raw, cosb, sinb);
  attn_kernel<<<dim3(NH * (TT/4)), 256, 0, stream>>>(q_raw, k_raw, v_raw, ybuf);
  gemm_proj <<<dim3(8,12), 256, 0, stream>>>(ybuf, Wp, out);
}

// Round 2
// 203.146 us; speedup vs baseline: 1.2282x; 1.2282x over previous
//
#include <hip/hip_runtime.h>
#include <math.h>

// Problem constants (B=1)
#define TT   512
#define CEMB 768
#define NH   12
#define NKV  6
#define HD   64
#define KVC  (NKV*HD)   // 384

__device__ __forceinline__ float wave_max(float v){
  #pragma unroll
  for(int o=32;o>0;o>>=1) v = fmaxf(v, __shfl_xor(v, o));
  return v;
}
__device__ __forceinline__ float wave_sum(float v){
  #pragma unroll
  for(int o=32;o>0;o>>=1) v += __shfl_xor(v, o);
  return v;
}

// ---- fp32 GEMM core: 32x64 tile, BK=32, 256 threads, 2x4 microtile ----
// Small tiles => 384/192 blocks => multiple blocks/CU co-resident for latency hiding.
__device__ __forceinline__ void gemm_core(const float* __restrict__ A,
                                          const float* __restrict__ B,
                                          float* __restrict__ C,
                                          int K, int lda, int ldb, int ldc,
                                          int m0, int n0){
  __shared__ float As[32][34];   // [k][m], stride 34: b64 reads aligned, writes 2-way (free)
  __shared__ float Bs[32][68];   // [k][n], stride 68: b128 aligned
  int tid  = threadIdx.x;
  int arow = tid >> 3, ak4 = (tid & 7) * 4;    // A stage: 32 rows x 32 k, one float4/thread
  int brow = tid >> 4, bc  = (tid & 15) * 4;   // B stage: 2 float4/thread (rows brow, brow+16)
  int ty   = tid >> 4, tx = tid & 15;          // microtile: rows {2ty,2ty+1}, cols tx*4..+3
  float acc[2][4];
  #pragma unroll
  for(int i=0;i<2;i++)
    #pragma unroll
    for(int j=0;j<4;j++) acc[i][j] = 0.f;

  for(int k0=0;k0<K;k0+=32){
    float4 a  = *(const float4*)(A + (size_t)(m0+arow)*lda + k0 + ak4);
    float4 b0 = *(const float4*)(B + (size_t)(k0+brow)*ldb + n0 + bc);
    float4 b1 = *(const float4*)(B + (size_t)(k0+brow+16)*ldb + n0 + bc);
    As[ak4+0][arow]=a.x; As[ak4+1][arow]=a.y; As[ak4+2][arow]=a.z; As[ak4+3][arow]=a.w;
    *(float4*)(&Bs[brow][bc])    = b0;
    *(float4*)(&Bs[brow+16][bc]) = b1;
    __syncthreads();
    #pragma unroll
    for(int kk=0;kk<32;kk++){
      float a0 = As[kk][2*ty+0];
      float a1 = As[kk][2*ty+1];
      float4 bv = *(float4*)(&Bs[kk][tx*4]);
      acc[0][0] = fmaf(a0, bv.x, acc[0][0]);
      acc[0][1] = fmaf(a0, bv.y, acc[0][1]);
      acc[0][2] = fmaf(a0, bv.z, acc[0][2]);
      acc[0][3] = fmaf(a0, bv.w, acc[0][3]);
      acc[1][0] = fmaf(a1, bv.x, acc[1][0]);
      acc[1][1] = fmaf(a1, bv.y, acc[1][1]);
      acc[1][2] = fmaf(a1, bv.z, acc[1][2]);
      acc[1][3] = fmaf(a1, bv.w, acc[1][3]);
    }
    __syncthreads();
  }
  #pragma unroll
  for(int i=0;i<2;i++){
    float4 o = make_float4(acc[i][0],acc[i][1],acc[i][2],acc[i][3]);
    *(float4*)(C + (size_t)(m0+2*ty+i)*ldc + n0 + tx*4) = o;
  }
}

// QKV projection: X(512x768) @ [Wq(768x768) | Wk(768x384) | Wv(768x384)]
__global__ void __launch_bounds__(256) gemm_qkv(const float* __restrict__ X,
    const float* __restrict__ Wq, const float* __restrict__ Wk, const float* __restrict__ Wv,
    float* __restrict__ q, float* __restrict__ k, float* __restrict__ v){
  int mt = blockIdx.x;       // 0..15
  int nt = blockIdx.y;       // 0..23
  const float* B; float* C; int ldb, ldc, n0;
  if (nt < 12)      { B = Wq; C = q; ldb = CEMB; ldc = CEMB; n0 = nt*64; }
  else if (nt < 18) { B = Wk; C = k; ldb = KVC;  ldc = KVC;  n0 = (nt-12)*64; }
  else              { B = Wv; C = v; ldb = KVC;  ldc = KVC;  n0 = (nt-18)*64; }
  gemm_core(X, B, C, CEMB, CEMB, ldb, ldc, mt*32, n0);
}

// Output projection: Y(512x768) @ Wproj(768x768)
__global__ void __launch_bounds__(256) gemm_proj(const float* __restrict__ Y,
    const float* __restrict__ Wp, float* __restrict__ C){
  gemm_core(Y, Wp, C, CEMB, CEMB, CEMB, CEMB, blockIdx.x*32, blockIdx.y*64);
}

// RoPE + RMSNorm, in-place on q (512x768) and k (512x384). One wave = one (t, head).
__global__ void __launch_bounds__(256) rope_rms(float* __restrict__ q, float* __restrict__ k,
    const float* __restrict__ cosb, const float* __restrict__ sinb){
  int wid  = (blockIdx.x * blockDim.x + threadIdx.x) >> 6;
  int lane = threadIdx.x & 63;
  float* base; int t;
  if (wid < TT*NH){
    t = wid / NH; int h = wid % NH;
    base = q + (size_t)t*CEMB + h*HD;
  } else {
    int w2 = wid - TT*NH;
    t = w2 / NKV; int h = w2 % NKV;
    base = k + (size_t)t*KVC + h*HD;
  }
  float v = base[lane];
  int dh = lane & 31;
  float c = cosb[t*32 + dh];
  float s = sinb[t*32 + dh];
  float partner = __shfl_xor(v, 32);
  float rot = (lane < 32) ? (v*c - partner*s) : (v*c + partner*s);
  float ss = wave_sum(rot*rot);
  float scale = rsqrtf(ss * (1.0f/64.0f) + 1e-6f);
  base[lane] = rot * scale;
}

// Tropical causal attention, flash-style online softmax.
// One block per (kvh, 8-row qblock): K/V tile shared across the 2 heads of the
// GQA group. 4 waves: waves 0,1 -> head 2*kvh (rows qb*8..+7), waves 2,3 -> head 2*kvh+1.
// Each wave owns 4 query rows.
__global__ void __launch_bounds__(256) attn_kernel(const float* __restrict__ qn,
    const float* __restrict__ kn, const float* __restrict__ vr, float* __restrict__ y){
  __shared__ float Ksh[64*65];
  __shared__ float Vsh[64*65];
  __shared__ float Qsh[16*64];
  __shared__ float Psh[4*64];
  int kvh  = blockIdx.x >> 6;     // 0..5
  int qb   = blockIdx.x & 63;     // 0..63
  int w    = threadIdx.x >> 6;    // 0..3
  int lane = threadIdx.x & 63;
  int hsel = w >> 1;              // 0 or 1
  int h    = kvh*2 + hsel;
  int r0   = qb*8 + (w&1)*4;      // first of this wave's 4 query rows
  int qsl  = hsel*8 + (w&1)*4;    // Qsh row slot base (per-wave private region)

  #pragma unroll
  for(int r=0;r<4;r++)
    Qsh[(qsl+r)*64 + lane] = qn[(size_t)(r0+r)*CEMB + h*HD + lane];

  float m[4], l[4], yacc[4];
  #pragma unroll
  for(int r=0;r<4;r++){ m[r] = -INFINITY; l[r] = 0.f; yacc[r] = 0.f; }

  int ntiles = qb/8 + 1;   // (qb*8+7)/64 + 1, block-uniform

  for(int tt=0; tt<ntiles; ++tt){
    int t0 = tt*64;
    __syncthreads();   // protect Ksh/Vsh reuse (also orders nothing cross-wave for Qsh: per-wave private)
    for(int rr=w; rr<64; rr+=4){
      Ksh[rr*65 + lane] = kn[(size_t)(t0+rr)*KVC + kvh*HD + lane];
      Vsh[rr*65 + lane] = vr[(size_t)(t0+rr)*KVC + kvh*HD + lane];
    }
    __syncthreads();

    #pragma unroll
    for(int r=0;r<4;r++){
      int i = r0 + r;
      if (t0 > i) continue;                 // wave-uniform
      const float* qrow = &Qsh[(qsl+r)*64];
      const float* krow = &Ksh[lane*65];
      float s = -INFINITY;
      #pragma unroll
      for(int d4=0; d4<64; d4+=4){
        float4 qv = *(const float4*)(qrow + d4);
        s = fmaxf(s, qv.x + krow[d4+0]);
        s = fmaxf(s, qv.y + krow[d4+1]);
        s = fmaxf(s, qv.z + krow[d4+2]);
        s = fmaxf(s, qv.w + krow[d4+3]);
      }
      if (t0 + lane > i) s = -INFINITY;     // causal mask

      float mt    = wave_max(s);
      float m_new = fmaxf(m[r], mt);
      float corr  = __expf(m[r] - m_new);   // 0 on first tile (m = -inf)
      float p     = __expf(s - m_new);      // 0 for masked lanes
      l[r]    = l[r]*corr + wave_sum(p);
      yacc[r] = yacc[r]*corr;

      Psh[w*64 + lane] = p;
      __builtin_amdgcn_wave_barrier();      // DS in-order per wave; block compiler reordering
      const float* prow = &Psh[w*64];
      #pragma unroll
      for(int j4=0;j4<64;j4+=4){
        float4 pv = *(const float4*)(prow + j4);
        yacc[r] = fmaf(pv.x, Vsh[(j4+0)*65 + lane], yacc[r]);
        yacc[r] = fmaf(pv.y, Vsh[(j4+1)*65 + lane], yacc[r]);
        yacc[r] = fmaf(pv.z, Vsh[(j4+2)*65 + lane], yacc[r]);
        yacc[r] = fmaf(pv.w, Vsh[(j4+3)*65 + lane], yacc[r]);
      }
      __builtin_amdgcn_wave_barrier();
      m[r] = m_new;
    }
  }
  #pragma unroll
  for(int r=0;r<4;r++)
    y[(size_t)(r0+r)*CEMB + h*HD + lane] = yacc[r] / l[r];
}

extern "C" void kernel_launch(void* const* d_in, const int* in_sizes, int n_in,
                              void* d_out, int out_size, void* d_ws, size_t ws_size,
                              hipStream_t stream){
  const float* x    = (const float*)d_in[0];
  const float* cosb = (const float*)d_in[1];
  const float* sinb = (const float*)d_in[2];
  const float* Wq   = (const float*)d_in[3];
  const float* Wk   = (const float*)d_in[4];
  const float* Wv   = (const float*)d_in[5];
  const float* Wp   = (const float*)d_in[6];
  float* out = (float*)d_out;

  float* ws    = (float*)d_ws;
  float* q_raw = ws;                          // 512*768
  float* k_raw = q_raw + TT*CEMB;             // 512*384
  float* v_raw = k_raw + TT*KVC;              // 512*384
  float* ybuf  = v_raw + TT*KVC;              // 512*768

  gemm_qkv  <<<dim3(16,24), 256, 0, stream>>>(x, Wq, Wk, Wv, q_raw, k_raw, v_raw);
  rope_rms  <<<dim3((TT*NH + TT*NKV)/4), 256, 0, stream>>>(q_raw, k_raw, cosb, sinb);
  attn_kernel<<<dim3(NKV*64), 256, 0, stream>>>(q_raw, k_raw, v_raw, ybuf);
  gemm_proj <<<dim3(16,12), 256, 0, stream>>>(ybuf, Wp, out);
}

// Round 3
// 176.213 us; speedup vs baseline: 1.4160x; 1.1528x over previous
//
#include <hip/hip_runtime.h>
#include <math.h>

// Problem constants (B=1)
#define TT   512
#define CEMB 768
#define NH   12
#define NKV  6
#define HD   64
#define KVC  (NKV*HD)   // 384

__device__ __forceinline__ float wave_max(float v){
  #pragma unroll
  for(int o=32;o>0;o>>=1) v = fmaxf(v, __shfl_xor(v, o));
  return v;
}
__device__ __forceinline__ float wave_sum(float v){
  #pragma unroll
  for(int o=32;o>0;o>>=1) v += __shfl_xor(v, o);
  return v;
}

// ---- fp32 GEMM core: 32x64 tile, BK=32, 256 threads, 2x4 microtile ----
// Global->reg prefetch pipeline: next K-chunk loads issue right after the
// barrier and complete during the 512-cyc FMA loop (latency hidden).
__device__ __forceinline__ void gemm_core(const float* __restrict__ A,
                                          const float* __restrict__ B,
                                          float* __restrict__ C,
                                          int K, int lda, int ldb, int ldc,
                                          int m0, int n0){
  __shared__ float As[32][34];   // [k][m]
  __shared__ float Bs[32][68];   // [k][n]
  int tid  = threadIdx.x;
  int arow = tid >> 3, ak4 = (tid & 7) * 4;    // A stage: 32 m x 32 k
  int brow = tid >> 4, bc  = (tid & 15) * 4;   // B stage: rows brow, brow+16
  int ty   = tid >> 4, tx = tid & 15;          // microtile rows {2ty,2ty+1}
  float acc[2][4];
  #pragma unroll
  for(int i=0;i<2;i++)
    #pragma unroll
    for(int j=0;j<4;j++) acc[i][j] = 0.f;

  const float* aptr = A + (size_t)(m0+arow)*lda + ak4;
  const float* bptr = B + (size_t)brow*ldb + n0 + bc;
  float4 a  = *(const float4*)(aptr);
  float4 b0 = *(const float4*)(bptr);
  float4 b1 = *(const float4*)(bptr + (size_t)16*ldb);

  for(int k0=0;k0<K;k0+=32){
    As[ak4+0][arow]=a.x; As[ak4+1][arow]=a.y; As[ak4+2][arow]=a.z; As[ak4+3][arow]=a.w;
    *(float4*)(&Bs[brow][bc])    = b0;
    *(float4*)(&Bs[brow+16][bc]) = b1;
    __syncthreads();
    if (k0 + 32 < K){
      a  = *(const float4*)(aptr + k0 + 32);
      b0 = *(const float4*)(bptr + (size_t)(k0+32)*ldb);
      b1 = *(const float4*)(bptr + (size_t)(k0+48)*ldb);
    }
    #pragma unroll
    for(int kk=0;kk<32;kk++){
      float a0 = As[kk][2*ty+0];
      float a1 = As[kk][2*ty+1];
      float4 bv = *(float4*)(&Bs[kk][tx*4]);
      acc[0][0] = fmaf(a0, bv.x, acc[0][0]);
      acc[0][1] = fmaf(a0, bv.y, acc[0][1]);
      acc[0][2] = fmaf(a0, bv.z, acc[0][2]);
      acc[0][3] = fmaf(a0, bv.w, acc[0][3]);
      acc[1][0] = fmaf(a1, bv.x, acc[1][0]);
      acc[1][1] = fmaf(a1, bv.y, acc[1][1]);
      acc[1][2] = fmaf(a1, bv.z, acc[1][2]);
      acc[1][3] = fmaf(a1, bv.w, acc[1][3]);
    }
    __syncthreads();
  }
  #pragma unroll
  for(int i=0;i<2;i++){
    float4 o = make_float4(acc[i][0],acc[i][1],acc[i][2],acc[i][3]);
    *(float4*)(C + (size_t)(m0+2*ty+i)*ldc + n0 + tx*4) = o;
  }
}

__global__ void __launch_bounds__(256) gemm_qkv(const float* __restrict__ X,
    const float* __restrict__ Wq, const float* __restrict__ Wk, const float* __restrict__ Wv,
    float* __restrict__ q, float* __restrict__ k, float* __restrict__ v){
  int mt = blockIdx.x;       // 0..15
  int nt = blockIdx.y;       // 0..23
  const float* B; float* C; int ldb, ldc, n0;
  if (nt < 12)      { B = Wq; C = q; ldb = CEMB; ldc = CEMB; n0 = nt*64; }
  else if (nt < 18) { B = Wk; C = k; ldb = KVC;  ldc = KVC;  n0 = (nt-12)*64; }
  else              { B = Wv; C = v; ldb = KVC;  ldc = KVC;  n0 = (nt-18)*64; }
  gemm_core(X, B, C, CEMB, CEMB, ldb, ldc, mt*32, n0);
}

__global__ void __launch_bounds__(256) gemm_proj(const float* __restrict__ Y,
    const float* __restrict__ Wp, float* __restrict__ C){
  gemm_core(Y, Wp, C, CEMB, CEMB, CEMB, CEMB, blockIdx.x*32, blockIdx.y*64);
}

// RoPE + RMSNorm, in-place on q (512x768) and k (512x384). One wave = one (t, head).
__global__ void __launch_bounds__(256) rope_rms(float* __restrict__ q, float* __restrict__ k,
    const float* __restrict__ cosb, const float* __restrict__ sinb){
  int wid  = (blockIdx.x * blockDim.x + threadIdx.x) >> 6;
  int lane = threadIdx.x & 63;
  float* base; int t;
  if (wid < TT*NH){
    t = wid / NH; int h = wid % NH;
    base = q + (size_t)t*CEMB + h*HD;
  } else {
    int w2 = wid - TT*NH;
    t = w2 / NKV; int h = w2 % NKV;
    base = k + (size_t)t*KVC + h*HD;
  }
  float v = base[lane];
  int dh = lane & 31;
  float c = cosb[t*32 + dh];
  float s = sinb[t*32 + dh];
  float partner = __shfl_xor(v, 32);
  float rot = (lane < 32) ? (v*c - partner*s) : (v*c + partner*s);
  float ss = wave_sum(rot*rot);
  float scale = rsqrtf(ss * (1.0f/64.0f) + 1e-6f);
  base[lane] = rot * scale;
}

// ---- Split-KV tropical attention ----
// Block = (kvh, qb: 8 q-rows, chunk: 128 kv rows => <=2 tiles of 64).
// 4 waves: wave w -> head kvh*2 + (w>>1), rows qb*8 + (w&1)*4 .. +3.
// Writes per-(h,row,chunk) partial (m, l, acc[64]); attn_reduce merges.
// LDS: K transposed [d][j] pad 65; V transposed [d][j] with 16B XOR swizzle.
__global__ void __launch_bounds__(256) attn_partial(const float* __restrict__ qn,
    const float* __restrict__ kn, const float* __restrict__ vr,
    float* __restrict__ part_acc, float2* __restrict__ part_ml){
  __shared__ float Ksh[64*65];   // K_t[d*65 + j]
  __shared__ float Vsh[64*64];   // V_t[d][j] swizzled
  __shared__ float Qsh[16*64];
  __shared__ float Psh[16*64];

  int kvh = blockIdx.y;          // 0..5
  int idx = blockIdx.x;          // 0..159
  int g, off;
  if      (idx < 16){ g=0; off=idx;    }
  else if (idx < 48){ g=1; off=idx-16; }
  else if (idx < 96){ g=2; off=idx-48; }
  else              { g=3; off=idx-96; }
  int qb    = g*16 + off/(g+1);
  int chunk = off - (off/(g+1))*(g+1);

  int w    = threadIdx.x >> 6;
  int lane = threadIdx.x & 63;
  int h    = kvh*2 + (w>>1);
  int r0   = qb*8 + (w&1)*4;
  int slot = w*4;                // Qsh/Psh row slots (per-wave private)

  #pragma unroll
  for(int r=0;r<4;r++)
    Qsh[(slot+r)*64 + lane] = qn[(size_t)(r0+r)*CEMB + h*HD + lane];

  float mr[4], lr[4], acc[4];
  #pragma unroll
  for(int r=0;r<4;r++){ mr[r] = -INFINITY; lr[r] = 0.f; acc[r] = 0.f; }

  int imax   = qb*8 + 7;
  int t0a    = chunk*128;
  int ntiles = (t0a + 64 <= imax) ? 2 : 1;   // block-uniform

  for(int tt=0; tt<ntiles; ++tt){
    int t0 = t0a + tt*64;
    if (tt) __syncthreads();     // protect LDS reuse between tiles
    // stage: 16 rows per wave, 4 rows per float4-load
    #pragma unroll
    for(int sub=0; sub<4; ++sub){
      int rr = w*16 + sub*4 + (lane>>4);     // local row (= j)
      int d0 = (lane&15)*4;
      const float4 k4 = *(const float4*)&kn[(size_t)(t0+rr)*KVC + kvh*HD + d0];
      const float4 v4 = *(const float4*)&vr[(size_t)(t0+rr)*KVC + kvh*HD + d0];
      #pragma unroll
      for(int c=0;c<4;c++){
        int d = d0 + c;
        Ksh[d*65 + rr] = (&k4.x)[c];
        Vsh[d*64 + ((((rr>>2) ^ (d&15))<<2) | (rr&3))] = (&v4.x)[c];
      }
    }
    __syncthreads();

    // scores: lane = j; K column reads amortized over 4 rows
    float sc[4] = {-INFINITY,-INFINITY,-INFINITY,-INFINITY};
    #pragma unroll
    for(int dg=0; dg<16; ++dg){
      float k0v = Ksh[(dg*4+0)*65 + lane];
      float k1v = Ksh[(dg*4+1)*65 + lane];
      float k2v = Ksh[(dg*4+2)*65 + lane];
      float k3v = Ksh[(dg*4+3)*65 + lane];
      #pragma unroll
      for(int r=0;r<4;r++){
        float4 q4 = *(const float4*)&Qsh[(slot+r)*64 + dg*4];
        sc[r] = fmaxf(sc[r], fmaxf(fmaxf(q4.x+k0v, q4.y+k1v),
                                   fmaxf(q4.z+k2v, q4.w+k3v)));
      }
    }
    // online softmax per row
    #pragma unroll
    for(int r=0;r<4;r++){
      int i = r0 + r;
      float s = (t0 + lane > i) ? -INFINITY : sc[r];
      float mt    = wave_max(s);
      float m_new = fmaxf(mr[r], mt);
      float mb    = (m_new == -INFINITY) ? 0.f : m_new;
      float corr  = __expf(mr[r] - mb);
      float p     = __expf(s - mb);
      lr[r] = lr[r]*corr + wave_sum(p);
      acc[r] *= corr;
      mr[r] = m_new;
      Psh[(slot+r)*64 + lane] = p;
    }
    __builtin_amdgcn_wave_barrier();
    // PV: lane = d; V row reads amortized over 4 rows
    #pragma unroll
    for(int jg=0; jg<16; ++jg){
      float4 vv = *(const float4*)&Vsh[lane*64 + ((jg ^ (lane&15))<<2)];
      #pragma unroll
      for(int r=0;r<4;r++){
        float4 p4 = *(const float4*)&Psh[(slot+r)*64 + jg*4];
        acc[r] = fmaf(p4.x, vv.x, fmaf(p4.y, vv.y,
                 fmaf(p4.z, vv.z, fmaf(p4.w, vv.w, acc[r]))));
      }
    }
    __builtin_amdgcn_wave_barrier();
  }

  #pragma unroll
  for(int r=0;r<4;r++){
    int i = r0 + r;
    int pidx = (h*TT + i)*4 + chunk;
    part_acc[(size_t)pidx*64 + lane] = acc[r];
    if (lane == 0) part_ml[pidx] = make_float2(mr[r], lr[r]);
  }
}

// Merge <=4 chunk partials per (h, row). One wave per row.
__global__ void __launch_bounds__(256) attn_reduce(const float* __restrict__ part_acc,
    const float2* __restrict__ part_ml, float* __restrict__ y){
  int wid  = (blockIdx.x * blockDim.x + threadIdx.x) >> 6;  // 0..6143
  int lane = threadIdx.x & 63;
  int h = wid >> 9;
  int i = wid & 511;
  int nch = (i >> 7) + 1;
  float m = -INFINITY, l = 0.f, a = 0.f;
  for(int c=0;c<nch;c++){
    int pidx = (h*TT + i)*4 + c;
    float2 ml = part_ml[pidx];
    float ac  = part_acc[(size_t)pidx*64 + lane];
    float m_new = fmaxf(m, ml.x);
    float sa  = __expf(m - m_new);      // c=0: exp(-inf)=0
    float sc_ = __expf(ml.x - m_new);   // all-masked chunk: 0
    l = l*sa + ml.y*sc_;
    a = a*sa + ac*sc_;
    m = m_new;
  }
  y[(size_t)i*CEMB + h*HD + lane] = a / l;
}

extern "C" void kernel_launch(void* const* d_in, const int* in_sizes, int n_in,
                              void* d_out, int out_size, void* d_ws, size_t ws_size,
                              hipStream_t stream){
  const float* x    = (const float*)d_in[0];
  const float* cosb = (const float*)d_in[1];
  const float* sinb = (const float*)d_in[2];
  const float* Wq   = (const float*)d_in[3];
  const float* Wk   = (const float*)d_in[4];
  const float* Wv   = (const float*)d_in[5];
  const float* Wp   = (const float*)d_in[6];
  float* out = (float*)d_out;

  float* ws       = (float*)d_ws;
  float* q_raw    = ws;                          // 512*768
  float* k_raw    = q_raw + TT*CEMB;             // 512*384
  float* v_raw    = k_raw + TT*KVC;              // 512*384
  float* ybuf     = v_raw + TT*KVC;              // 512*768
  float* part_acc = ybuf + TT*CEMB;              // 12*512*4*64
  float2* part_ml = (float2*)(part_acc + (size_t)NH*TT*4*64);  // 12*512*4

  gemm_qkv    <<<dim3(16,24), 256, 0, stream>>>(x, Wq, Wk, Wv, q_raw, k_raw, v_raw);
  rope_rms    <<<dim3((TT*NH + TT*NKV)/4), 256, 0, stream>>>(q_raw, k_raw, cosb, sinb);
  attn_partial<<<dim3(160, NKV), 256, 0, stream>>>(q_raw, k_raw, v_raw, part_acc, part_ml);
  attn_reduce <<<dim3(NH*TT/4), 256, 0, stream>>>(part_acc, part_ml, ybuf);
  gemm_proj   <<<dim3(16,12), 256, 0, stream>>>(ybuf, Wp, out);
}